// Round 1
// baseline (195.346 us; speedup 1.0000x reference)
//
#include <hip/hip_runtime.h>

#define B_ 8
#define Q_ 64
#define K_ 512
#define NU_ 512
#define D_ 512

// ---------------------------------------------------------------------------
// Kernel 1: v = (linear_att / ||linear_att||) * normalize_scalar[0]
// ---------------------------------------------------------------------------
__global__ __launch_bounds__(512) void compute_v_kernel(
    const float* __restrict__ la, const float* __restrict__ scalar,
    float* __restrict__ v) {
  __shared__ float red[8];
  int t = threadIdx.x;  // 512 threads
  float x = la[t];
  float ss = x * x;
#pragma unroll
  for (int o = 1; o < 64; o <<= 1) ss += __shfl_xor(ss, o, 64);
  int wave = t >> 6, lane = t & 63;
  if (lane == 0) red[wave] = ss;
  __syncthreads();
  float tot = 0.f;
#pragma unroll
  for (int w = 0; w < 8; w++) tot += red[w];
  v[t] = x * rsqrtf(tot) * scalar[0];
}

// ---------------------------------------------------------------------------
// Kernel 2: C[b,m,n] = sum_d A[b,m,d] * Bm[n,d]  (+ bias[n] if given)
// A: [batch, M, 512] row-major, Bm: [512, 512] row-major, C: [batch, M, 512]
// 64x64 tile, 256 threads, 4x4 per thread, d-step 16.
// ---------------------------------------------------------------------------
__global__ __launch_bounds__(256) void gemm_nt_kernel(
    const float* __restrict__ A, const float* __restrict__ Bm,
    float* __restrict__ C, const float* __restrict__ bias, int M) {
  __shared__ __align__(16) float As[16][68];
  __shared__ __align__(16) float Bs[16][68];
  int b = blockIdx.z;
  const float* Ab = A + (size_t)b * M * D_;
  float* Cb = C + (size_t)b * M * NU_;
  int m0 = blockIdx.x * 64, n0 = blockIdx.y * 64;
  int t = threadIdx.x;
  int tx = t & 15, ty = t >> 4;  // compute coords: rows ty*4+i, cols tx*4+j
  int ld = t & 15, lm = t >> 4;  // load coords
  float acc[4][4] = {};
  for (int d0 = 0; d0 < D_; d0 += 16) {
#pragma unroll
    for (int r = 0; r < 4; r++) {
      As[ld][lm + 16 * r] = Ab[(size_t)(m0 + lm + 16 * r) * D_ + d0 + ld];
      Bs[ld][lm + 16 * r] = Bm[(size_t)(n0 + lm + 16 * r) * D_ + d0 + ld];
    }
    __syncthreads();
#pragma unroll
    for (int dd = 0; dd < 16; dd++) {
      float4 a4 = *reinterpret_cast<const float4*>(&As[dd][ty * 4]);
      float4 b4 = *reinterpret_cast<const float4*>(&Bs[dd][tx * 4]);
      float av[4] = {a4.x, a4.y, a4.z, a4.w};
      float bv[4] = {b4.x, b4.y, b4.z, b4.w};
#pragma unroll
      for (int i = 0; i < 4; i++)
#pragma unroll
        for (int j = 0; j < 4; j++)
          acc[i][j] = fmaf(av[i], bv[j], acc[i][j]);
    }
    __syncthreads();
  }
#pragma unroll
  for (int i = 0; i < 4; i++) {
    int row = m0 + ty * 4 + i;
    float4 o;
    float* op = &o.x;
#pragma unroll
    for (int j = 0; j < 4; j++) {
      float val = acc[i][j];
      if (bias) val += bias[n0 + tx * 4 + j];
      op[j] = val;
    }
    *reinterpret_cast<float4*>(&Cb[(size_t)row * NU_ + n0 + tx * 4]) = o;
  }
}

// ---------------------------------------------------------------------------
// Kernel 3: per (b,q) block: scores -> softmax -> context
// scores[k] = sum_u tanh(pq[u] + pk[k,u]) * v[u]   (bias already in pq)
// ---------------------------------------------------------------------------
__global__ __launch_bounds__(256) void attn_kernel(
    const float* __restrict__ pq, const float* __restrict__ pk,
    const float* __restrict__ keys, const float* __restrict__ v,
    float* __restrict__ ctx, float* __restrict__ smx) {
  __shared__ __align__(16) float sPq[NU_];
  __shared__ __align__(16) float sV[NU_];
  __shared__ float sScore[K_];
  __shared__ float red[8];
  int bq = blockIdx.x;
  int b = bq >> 6;
  const float* pqr = pq + (size_t)bq * NU_;
  const float* pkb = pk + (size_t)b * K_ * NU_;
  const float* keysb = keys + (size_t)b * K_ * D_;
  int t = threadIdx.x;
  sPq[t] = pqr[t];
  sPq[t + 256] = pqr[t + 256];
  sV[t] = v[t];
  sV[t + 256] = v[t + 256];
  __syncthreads();

  int wave = t >> 6, lane = t & 63;
  int ksub = lane >> 3;      // 0..7 : which k row within the wave's 8
  int uoff = (lane & 7) * 4; // 0,4,..,28 : float4 offset in u
  const float C2 = 2.8853900817779268f;  // 2*log2(e)

  for (int kb = 0; kb < K_; kb += 32) {
    int k = kb + wave * 8 + ksub;
    const float* pkr = pkb + (size_t)k * NU_;
    float acc = 0.f;
#pragma unroll
    for (int j = 0; j < 16; j++) {
      int u = uoff + 32 * j;
      float4 pk4 = *reinterpret_cast<const float4*>(&pkr[u]);
      float4 pq4 = *reinterpret_cast<const float4*>(&sPq[u]);
      float4 v4 = *reinterpret_cast<const float4*>(&sV[u]);
      float xs[4] = {pk4.x + pq4.x, pk4.y + pq4.y, pk4.z + pq4.z,
                     pk4.w + pq4.w};
      float vs[4] = {v4.x, v4.y, v4.z, v4.w};
#pragma unroll
      for (int i = 0; i < 4; i++) {
        float e = __builtin_amdgcn_exp2f(xs[i] * C2);
        float r = __builtin_amdgcn_rcpf(1.f + e);
        float th = fmaf(-2.f, r, 1.f);  // tanh(x)
        acc = fmaf(vs[i], th, acc);
      }
    }
    acc += __shfl_xor(acc, 1, 64);
    acc += __shfl_xor(acc, 2, 64);
    acc += __shfl_xor(acc, 4, 64);
    if ((lane & 7) == 0) sScore[k] = acc;
  }
  __syncthreads();

  // ---- softmax over the 512 scores (normalized output only) ----
  float s0 = sScore[t], s1 = sScore[t + 256];
  float m = fmaxf(s0, s1);
#pragma unroll
  for (int o = 1; o < 64; o <<= 1) m = fmaxf(m, __shfl_xor(m, o, 64));
  if (lane == 0) red[wave] = m;
  __syncthreads();
  float gm = fmaxf(fmaxf(red[0], red[1]), fmaxf(red[2], red[3]));
  const float L2E = 1.4426950408889634f;
  float e0 = __builtin_amdgcn_exp2f((s0 - gm) * L2E);
  float e1 = __builtin_amdgcn_exp2f((s1 - gm) * L2E);
  float sum = e0 + e1;
#pragma unroll
  for (int o = 1; o < 64; o <<= 1) sum += __shfl_xor(sum, o, 64);
  if (lane == 0) red[4 + wave] = sum;
  __syncthreads();
  float tot = red[4] + red[5] + red[6] + red[7];
  float inv = 1.f / tot;
  smx[(size_t)bq * K_ + t] = e0 * inv;
  smx[(size_t)bq * K_ + t + 256] = e1 * inv;

  // ---- context = raw scores @ keys ----
  float c0 = 0.f, c1 = 0.f;
#pragma unroll 8
  for (int k = 0; k < K_; k++) {
    float s = sScore[k];
    c0 = fmaf(s, keysb[(size_t)k * D_ + t], c0);
    c1 = fmaf(s, keysb[(size_t)k * D_ + t + 256], c1);
  }
  ctx[(size_t)bq * D_ + t] = c0;
  ctx[(size_t)bq * D_ + t + 256] = c1;
}

// ---------------------------------------------------------------------------
extern "C" void kernel_launch(void* const* d_in, const int* in_sizes, int n_in,
                              void* d_out, int out_size, void* d_ws,
                              size_t ws_size, hipStream_t stream) {
  const float* query = (const float*)d_in[0];   // [8,64,512]
  const float* keys = (const float*)d_in[1];    // [8,512,512]
  const float* Wq = (const float*)d_in[2];      // [512,512]
  const float* Wk = (const float*)d_in[3];      // [512,512]
  const float* la = (const float*)d_in[4];      // [512]
  const float* nscalar = (const float*)d_in[5]; // [1]
  const float* nbias = (const float*)d_in[6];   // [512]

  float* out = (float*)d_out;
  float* ctx = out;                       // [8,64,512]
  float* smx = out + (size_t)B_ * Q_ * D_; // [8,64,512]

  float* ws = (float*)d_ws;
  float* v = ws;                   // 512
  float* pq = ws + 512;            // 8*64*512   = 262144
  float* pk = pq + B_ * Q_ * NU_;  // 8*512*512  = 2097152

  compute_v_kernel<<<1, 512, 0, stream>>>(la, nscalar, v);
  // pq = query @ Wq^T + bias   (M=64)
  gemm_nt_kernel<<<dim3(1, 8, B_), 256, 0, stream>>>(query, Wq, pq, nbias, Q_);
  // pk = keys @ Wk^T           (M=512)
  gemm_nt_kernel<<<dim3(8, 8, B_), 256, 0, stream>>>(keys, Wk, pk, nullptr, K_);
  // fused scores -> softmax -> context
  attn_kernel<<<B_ * Q_, 256, 0, stream>>>(pq, pk, keys, v, ctx, smx);
}

// Round 2
// 120.504 us; speedup vs baseline: 1.6211x; 1.6211x over previous
//
#include <hip/hip_runtime.h>

#define B_ 8
#define Q_ 64
#define K_ 512
#define NU_ 512
#define D_ 512

// ---------------------------------------------------------------------------
// Kernel 1: v = (linear_att / ||linear_att||) * normalize_scalar[0]
// ---------------------------------------------------------------------------
__global__ __launch_bounds__(512) void compute_v_kernel(
    const float* __restrict__ la, const float* __restrict__ scalar,
    float* __restrict__ v) {
  __shared__ float red[8];
  int t = threadIdx.x;  // 512 threads
  float x = la[t];
  float ss = x * x;
#pragma unroll
  for (int o = 1; o < 64; o <<= 1) ss += __shfl_xor(ss, o, 64);
  int wave = t >> 6, lane = t & 63;
  if (lane == 0) red[wave] = ss;
  __syncthreads();
  float tot = 0.f;
#pragma unroll
  for (int w = 0; w < 8; w++) tot += red[w];
  v[t] = x * rsqrtf(tot) * scalar[0];
}

// ---------------------------------------------------------------------------
// Kernel 2: merged projection GEMM.
// blockIdx.x (0..71): <8 -> pq tile (query @ Wq^T + bias), else pk tile
// (keys @ Wk^T). All "A" matrices are flat [rows, 512] row-major; every
// block owns a 64-row x 64-col output tile.
// ---------------------------------------------------------------------------
__global__ __launch_bounds__(256) void proj_gemm_kernel(
    const float* __restrict__ query, const float* __restrict__ keys,
    const float* __restrict__ Wq, const float* __restrict__ Wk,
    const float* __restrict__ bias, float* __restrict__ pq,
    float* __restrict__ pk) {
  __shared__ __align__(16) float As[16][68];
  __shared__ __align__(16) float Bs[16][68];
  int mt = blockIdx.x;
  int n0 = blockIdx.y * 64;
  const float* A;
  const float* W;
  float* C;
  bool ub;
  if (mt < 8) {
    A = query + (size_t)mt * 64 * D_;
    W = Wq;
    C = pq + (size_t)mt * 64 * NU_;
    ub = true;
  } else {
    A = keys + (size_t)(mt - 8) * 64 * D_;
    W = Wk;
    C = pk + (size_t)(mt - 8) * 64 * NU_;
    ub = false;
  }
  int t = threadIdx.x;
  int tx = t & 15, ty = t >> 4;
  int ld = t & 15, lm = t >> 4;
  float acc[4][4] = {};
  for (int d0 = 0; d0 < D_; d0 += 16) {
#pragma unroll
    for (int r = 0; r < 4; r++) {
      As[ld][lm + 16 * r] = A[(size_t)(lm + 16 * r) * D_ + d0 + ld];
      Bs[ld][lm + 16 * r] = W[(size_t)(n0 + lm + 16 * r) * D_ + d0 + ld];
    }
    __syncthreads();
#pragma unroll
    for (int dd = 0; dd < 16; dd++) {
      float4 a4 = *reinterpret_cast<const float4*>(&As[dd][ty * 4]);
      float4 b4 = *reinterpret_cast<const float4*>(&Bs[dd][tx * 4]);
      float av[4] = {a4.x, a4.y, a4.z, a4.w};
      float bv[4] = {b4.x, b4.y, b4.z, b4.w};
#pragma unroll
      for (int i = 0; i < 4; i++)
#pragma unroll
        for (int j = 0; j < 4; j++)
          acc[i][j] = fmaf(av[i], bv[j], acc[i][j]);
    }
    __syncthreads();
  }
#pragma unroll
  for (int i = 0; i < 4; i++) {
    float4 o;
    float* op = &o.x;
#pragma unroll
    for (int j = 0; j < 4; j++) {
      float val = acc[i][j];
      if (ub) val += bias[n0 + tx * 4 + j];
      op[j] = val;
    }
    *reinterpret_cast<float4*>(&C[(size_t)(ty * 4 + i) * NU_ + n0 + tx * 4]) = o;
  }
}

// ---------------------------------------------------------------------------
// Kernel 3: scores tile. Block = (b, qtile of 8, ktile of 64).
// S[b,q,k] = sum_u tanh(pq[b,q,u] + pk[b,k,u]) * v[u]
// Each thread: one k row, 4-u-lane slice, 8 independent q accumulators.
// ---------------------------------------------------------------------------
__global__ __launch_bounds__(256) void scores_kernel(
    const float* __restrict__ pq, const float* __restrict__ pk,
    const float* __restrict__ v, float* __restrict__ S) {
  __shared__ __align__(16) float sPq[8][NU_];  // 16 KB
  __shared__ __align__(16) float sV[NU_];      // 2 KB
  int b = blockIdx.x >> 3, qt = blockIdx.x & 7, kt = blockIdx.y;
  int q0 = qt * 8, k0 = kt * 64;
  int t = threadIdx.x;
  const float4* pqsrc =
      reinterpret_cast<const float4*>(pq + ((size_t)b * Q_ + q0) * NU_);
#pragma unroll
  for (int i = 0; i < 4; i++)
    reinterpret_cast<float4*>(&sPq[0][0])[t + 256 * i] = pqsrc[t + 256 * i];
  if (t < 128)
    reinterpret_cast<float4*>(sV)[t] = reinterpret_cast<const float4*>(v)[t];
  __syncthreads();

  int wave = t >> 6, lane = t & 63;
  int ksub = lane >> 2, ulane = lane & 3;
  int k = k0 + wave * 16 + ksub;
  const float* pkr = pk + ((size_t)b * K_ + k) * NU_;
  float acc[8] = {};
  const float C2 = 2.8853900817779268f;  // 2*log2(e)
#pragma unroll 4
  for (int j = 0; j < 32; j++) {
    int u = j * 16 + ulane * 4;
    float4 pk4 = *reinterpret_cast<const float4*>(&pkr[u]);
    float4 v4 = *reinterpret_cast<const float4*>(&sV[u]);
    float pkv[4] = {pk4.x, pk4.y, pk4.z, pk4.w};
    float vv[4] = {v4.x, v4.y, v4.z, v4.w};
#pragma unroll
    for (int qq = 0; qq < 8; qq++) {
      float4 pq4 = *reinterpret_cast<const float4*>(&sPq[qq][u]);
      float pqv[4] = {pq4.x, pq4.y, pq4.z, pq4.w};
#pragma unroll
      for (int i = 0; i < 4; i++) {
        float e = __builtin_amdgcn_exp2f((pkv[i] + pqv[i]) * C2);
        float r = __builtin_amdgcn_rcpf(1.f + e);
        acc[qq] = fmaf(vv[i], fmaf(-2.f, r, 1.f), acc[qq]);
      }
    }
  }
#pragma unroll
  for (int qq = 0; qq < 8; qq++) {
    float a = acc[qq];
    a += __shfl_xor(a, 1, 64);
    a += __shfl_xor(a, 2, 64);
    if (ulane == 0) S[((size_t)b * Q_ + q0 + qq) * K_ + k] = a;
  }
}

// ---------------------------------------------------------------------------
// Kernel 4: softmax (dt==0 blocks) + context. Block = (b, qtile 8, dtile 64).
// Stages S tile [8][512] and keys chunks [64][64] in LDS.
// ---------------------------------------------------------------------------
__global__ __launch_bounds__(256) void ctx_kernel(
    const float* __restrict__ S, const float* __restrict__ keys,
    float* __restrict__ ctx, float* __restrict__ smx) {
  __shared__ __align__(16) float sS[8][K_];   // 16 KB
  __shared__ __align__(16) float sK[64][64];  // 16 KB
  int b = blockIdx.x >> 3, qt = blockIdx.x & 7, dt = blockIdx.y;
  int q0 = qt * 8, d0 = dt * 64;
  int t = threadIdx.x;
  const float4* ssrc =
      reinterpret_cast<const float4*>(S + ((size_t)b * Q_ + q0) * K_);
#pragma unroll
  for (int i = 0; i < 4; i++)
    reinterpret_cast<float4*>(&sS[0][0])[t + 256 * i] = ssrc[t + 256 * i];
  __syncthreads();

  int q = t >> 5, lg = t & 31;
  // softmax stats over this q's 512 raw scores (32-lane group per q)
  float m = -1e30f;
  for (int kk = lg; kk < K_; kk += 32) m = fmaxf(m, sS[q][kk]);
#pragma unroll
  for (int o = 1; o < 32; o <<= 1) m = fmaxf(m, __shfl_xor(m, o, 64));
  const float L2E = 1.4426950408889634f;
  float sum = 0.f;
  for (int kk = lg; kk < K_; kk += 32)
    sum += __builtin_amdgcn_exp2f((sS[q][kk] - m) * L2E);
#pragma unroll
  for (int o = 1; o < 32; o <<= 1) sum += __shfl_xor(sum, o, 64);
  if (dt == 0) {
    float inv = 1.f / sum;
    float* dst = smx + ((size_t)b * Q_ + q0 + q) * K_;
    for (int kk = lg; kk < K_; kk += 32)
      dst[kk] = __builtin_amdgcn_exp2f((sS[q][kk] - m) * L2E) * inv;
  }

  // context: ctx[q, d0+2*lg .. +1] = sum_k rawS[q,k] * keys[k,d]
  float c0 = 0.f, c1 = 0.f;
  const float* keysb = keys + (size_t)b * K_ * D_ + d0;
  for (int kc = 0; kc < K_; kc += 64) {
    __syncthreads();
    for (int i = t; i < 64 * 16; i += 256) {
      int row = i >> 4, c4 = i & 15;
      reinterpret_cast<float4*>(&sK[row][0])[c4] =
          *reinterpret_cast<const float4*>(&keysb[(size_t)(kc + row) * D_ + c4 * 4]);
    }
    __syncthreads();
#pragma unroll 8
    for (int kk = 0; kk < 64; kk++) {
      float s = sS[q][kc + kk];
      float2 kv = *reinterpret_cast<const float2*>(&sK[kk][lg * 2]);
      c0 = fmaf(s, kv.x, c0);
      c1 = fmaf(s, kv.y, c1);
    }
  }
  float2 o2 = {c0, c1};
  *reinterpret_cast<float2*>(
      &ctx[((size_t)b * Q_ + q0 + q) * D_ + d0 + lg * 2]) = o2;
}

// ---------------------------------------------------------------------------
extern "C" void kernel_launch(void* const* d_in, const int* in_sizes, int n_in,
                              void* d_out, int out_size, void* d_ws,
                              size_t ws_size, hipStream_t stream) {
  const float* query = (const float*)d_in[0];    // [8,64,512]
  const float* keys = (const float*)d_in[1];     // [8,512,512]
  const float* Wq = (const float*)d_in[2];       // [512,512]
  const float* Wk = (const float*)d_in[3];       // [512,512]
  const float* la = (const float*)d_in[4];       // [512]
  const float* nscalar = (const float*)d_in[5];  // [1]
  const float* nbias = (const float*)d_in[6];    // [512]

  float* out = (float*)d_out;
  float* ctx = out;                        // [8,64,512]
  float* smx = out + (size_t)B_ * Q_ * D_;  // [8,64,512]

  float* ws = (float*)d_ws;
  float* v = ws;                    // 512
  float* pq = ws + 512;             // 8*64*512
  float* pk = pq + B_ * Q_ * NU_;   // 8*512*512
  float* S = pk + (size_t)B_ * K_ * NU_;  // 8*64*512

  compute_v_kernel<<<1, 512, 0, stream>>>(la, nscalar, v);
  proj_gemm_kernel<<<dim3(72, 8), 256, 0, stream>>>(query, keys, Wq, Wk, nbias,
                                                    pq, pk);
  scores_kernel<<<dim3(64, 8), 256, 0, stream>>>(pq, pk, v, S);
  ctx_kernel<<<dim3(64, 8), 256, 0, stream>>>(S, keys, ctx, smx);
}

// Round 3
// 86.838 us; speedup vs baseline: 2.2495x; 1.3877x over previous
//
#include <hip/hip_runtime.h>

#define B_ 8
#define Q_ 64
#define K_ 512
#define NU_ 512
#define D_ 512

typedef __attribute__((ext_vector_type(8))) _Float16 half8;
typedef __attribute__((ext_vector_type(4))) _Float16 half4;
typedef __attribute__((ext_vector_type(16))) float floatx16;

// ws float-layout
#define WS_V 0
#define WS_PQ 512
#define WS_PK (512 + 262144)
#define WS_S (512 + 262144 + 2097152)
#define WS_FLOATS (512 + 262144 + 2097152 + 262144)  // 2621952
// half region starts at float index WS_FLOATS (byte 10487808, 16B aligned)
#define AH_ELEMS 2359296   // 4608*512 (keys rows 0..4095, query rows 4096..4607)
#define WH_ELEMS 262144    // 512*512
#define WS_BYTES_MFMA (WS_FLOATS * 4 + (AH_ELEMS + 2 * WH_ELEMS) * 2)
#define WS_BYTES_FALLBACK (WS_FLOATS * 4)

// ---------------------------------------------------------------------------
// Kernel 1: fused f32->f16 conversion (keys, query, Wk, Wq) + v-normalize.
// Blocks 0..2815 convert 4-float chunks; block 2816 computes v.
// ---------------------------------------------------------------------------
#define CHUNKS_KEYS 524288
#define CHUNKS_Q 65536
#define CHUNKS_W 65536
#define CONV_BLOCKS 2816  // (524288+65536*3)/256

__global__ __launch_bounds__(256) void convert_kernel(
    const float* __restrict__ query, const float* __restrict__ keys,
    const float* __restrict__ Wq, const float* __restrict__ Wk,
    const float* __restrict__ la, const float* __restrict__ scalar,
    _Float16* __restrict__ Ah, _Float16* __restrict__ Wkh,
    _Float16* __restrict__ Wqh, float* __restrict__ v) {
  int bid = blockIdx.x;
  int t = threadIdx.x;
  if (bid == CONV_BLOCKS) {
    __shared__ float red[4];
    float x0 = la[t], x1 = la[t + 256];
    float ss = x0 * x0 + x1 * x1;
#pragma unroll
    for (int o = 1; o < 64; o <<= 1) ss += __shfl_xor(ss, o, 64);
    int wave = t >> 6, lane = t & 63;
    if (lane == 0) red[wave] = ss;
    __syncthreads();
    float tot = red[0] + red[1] + red[2] + red[3];
    float sc = rsqrtf(tot) * scalar[0];
    v[t] = x0 * sc;
    v[t + 256] = x1 * sc;
    return;
  }
  int c = bid * 256 + t;
  const float* src;
  _Float16* dst;
  if (c < CHUNKS_KEYS) {
    src = keys;
    dst = Ah;
  } else if (c < CHUNKS_KEYS + CHUNKS_Q) {
    src = query;
    dst = Ah + 2097152;
    c -= CHUNKS_KEYS;
  } else if (c < CHUNKS_KEYS + CHUNKS_Q + CHUNKS_W) {
    src = Wk;
    dst = Wkh;
    c -= CHUNKS_KEYS + CHUNKS_Q;
  } else {
    src = Wq;
    dst = Wqh;
    c -= CHUNKS_KEYS + CHUNKS_Q + CHUNKS_W;
  }
  float4 x = reinterpret_cast<const float4*>(src)[c];
  half4 o = {(_Float16)x.x, (_Float16)x.y, (_Float16)x.z, (_Float16)x.w};
  *reinterpret_cast<half4*>(dst + (size_t)c * 4) = o;
}

// ---------------------------------------------------------------------------
// Kernel 2: MFMA projection GEMM. C[m,n] = sum_d A[m,d]*W[n,d] over the
// flattened 4608x512 row space (rows<4096: keys->pk, else query->pq+bias).
// 64x64 tile per block, 4 waves of 32x32 via mfma_f32_32x32x16_f16.
// ---------------------------------------------------------------------------
__global__ __launch_bounds__(256) void mfma_proj_kernel(
    const _Float16* __restrict__ Ah, const _Float16* __restrict__ Wkh,
    const _Float16* __restrict__ Wqh, const float* __restrict__ bias,
    float* __restrict__ pk, float* __restrict__ pq) {
  __shared__ _Float16 sA[64][40];  // 80B row stride: 16B aligned, 2-way banks
  __shared__ _Float16 sW[64][40];
  int m0 = blockIdx.x * 64, n0 = blockIdx.y * 64;
  bool isQ = (m0 >= 4096);
  const _Float16* W = isQ ? Wqh : Wkh;
  int t = threadIdx.x;
  // staging: each thread owns one 16B chunk of A tile and one of W tile
  int crow = t >> 2, cq = t & 3;
  const _Float16* gA = Ah + (size_t)(m0 + crow) * 512 + cq * 8;
  const _Float16* gW = W + (size_t)(n0 + crow) * 512 + cq * 8;
  _Float16* lA = &sA[crow][cq * 8];
  _Float16* lW = &sW[crow][cq * 8];
  // fragment coords
  int wave = t >> 6, lane = t & 63;
  int mw = (wave >> 1) * 32, nw = (wave & 1) * 32;
  int lr = lane & 31, g = lane >> 5;
  const _Float16* rdA0 = &sA[mw + lr][g * 8];
  const _Float16* rdA1 = &sA[mw + lr][16 + g * 8];
  const _Float16* rdW0 = &sW[nw + lr][g * 8];
  const _Float16* rdW1 = &sW[nw + lr][16 + g * 8];
  floatx16 acc;
#pragma unroll
  for (int i = 0; i < 16; i++) acc[i] = 0.f;
  for (int k0 = 0; k0 < 512; k0 += 32) {
    half8 va = *reinterpret_cast<const half8*>(gA + k0);
    half8 vw = *reinterpret_cast<const half8*>(gW + k0);
    __syncthreads();  // previous iteration's fragment reads complete
    *reinterpret_cast<half8*>(lA) = va;
    *reinterpret_cast<half8*>(lW) = vw;
    __syncthreads();
    half8 a0 = *reinterpret_cast<const half8*>(rdA0);
    half8 a1 = *reinterpret_cast<const half8*>(rdA1);
    half8 w0 = *reinterpret_cast<const half8*>(rdW0);
    half8 w1 = *reinterpret_cast<const half8*>(rdW1);
    acc = __builtin_amdgcn_mfma_f32_32x32x16_f16(a0, w0, acc, 0, 0, 0);
    acc = __builtin_amdgcn_mfma_f32_32x32x16_f16(a1, w1, acc, 0, 0, 0);
  }
  int col = n0 + nw + lr;
  float bv = isQ ? bias[col] : 0.f;
#pragma unroll
  for (int r = 0; r < 16; r++) {
    int mrow = m0 + mw + (r & 3) + 8 * (r >> 2) + 4 * g;
    if (isQ)
      pq[(size_t)(mrow - 4096) * NU_ + col] = acc[r] + bv;
    else
      pk[(size_t)mrow * NU_ + col] = acc[r];
  }
}

// ---------------------------------------------------------------------------
// Fallback path (ws too small): f32 kernels from round 2
// ---------------------------------------------------------------------------
__global__ __launch_bounds__(512) void compute_v_kernel(
    const float* __restrict__ la, const float* __restrict__ scalar,
    float* __restrict__ v) {
  __shared__ float red[8];
  int t = threadIdx.x;
  float x = la[t];
  float ss = x * x;
#pragma unroll
  for (int o = 1; o < 64; o <<= 1) ss += __shfl_xor(ss, o, 64);
  int wave = t >> 6, lane = t & 63;
  if (lane == 0) red[wave] = ss;
  __syncthreads();
  float tot = 0.f;
#pragma unroll
  for (int w = 0; w < 8; w++) tot += red[w];
  v[t] = x * rsqrtf(tot) * scalar[0];
}

__global__ __launch_bounds__(256) void proj_gemm_kernel(
    const float* __restrict__ query, const float* __restrict__ keys,
    const float* __restrict__ Wq, const float* __restrict__ Wk,
    const float* __restrict__ bias, float* __restrict__ pq,
    float* __restrict__ pk) {
  __shared__ __align__(16) float As[16][68];
  __shared__ __align__(16) float Bs[16][68];
  int mt = blockIdx.x;
  int n0 = blockIdx.y * 64;
  const float* A;
  const float* W;
  float* C;
  bool ub;
  if (mt < 8) {
    A = query + (size_t)mt * 64 * D_;
    W = Wq;
    C = pq + (size_t)mt * 64 * NU_;
    ub = true;
  } else {
    A = keys + (size_t)(mt - 8) * 64 * D_;
    W = Wk;
    C = pk + (size_t)(mt - 8) * 64 * NU_;
    ub = false;
  }
  int t = threadIdx.x;
  int tx = t & 15, ty = t >> 4;
  int ld = t & 15, lm = t >> 4;
  float acc[4][4] = {};
  for (int d0 = 0; d0 < D_; d0 += 16) {
#pragma unroll
    for (int r = 0; r < 4; r++) {
      As[ld][lm + 16 * r] = A[(size_t)(lm + 16 * r) * D_ + d0 + ld];
      Bs[ld][lm + 16 * r] = W[(size_t)(n0 + lm + 16 * r) * D_ + d0 + ld];
    }
    __syncthreads();
#pragma unroll
    for (int dd = 0; dd < 16; dd++) {
      float4 a4 = *reinterpret_cast<const float4*>(&As[dd][ty * 4]);
      float4 b4 = *reinterpret_cast<const float4*>(&Bs[dd][tx * 4]);
      float av[4] = {a4.x, a4.y, a4.z, a4.w};
      float bv[4] = {b4.x, b4.y, b4.z, b4.w};
#pragma unroll
      for (int i = 0; i < 4; i++)
#pragma unroll
        for (int j = 0; j < 4; j++)
          acc[i][j] = fmaf(av[i], bv[j], acc[i][j]);
    }
    __syncthreads();
  }
#pragma unroll
  for (int i = 0; i < 4; i++) {
    float4 o;
    float* op = &o.x;
#pragma unroll
    for (int j = 0; j < 4; j++) {
      float val = acc[i][j];
      if (ub) val += bias[n0 + tx * 4 + j];
      op[j] = val;
    }
    *reinterpret_cast<float4*>(&C[(size_t)(ty * 4 + i) * NU_ + n0 + tx * 4]) = o;
  }
}

// ---------------------------------------------------------------------------
// Kernel 3: scores tile. Block = (b, qtile of 8, ktile of 64).
// S[b,q,k] = sum_u tanh(pq[b,q,u] + pk[b,k,u]) * v[u]
// ---------------------------------------------------------------------------
__global__ __launch_bounds__(256) void scores_kernel(
    const float* __restrict__ pq, const float* __restrict__ pk,
    const float* __restrict__ v, float* __restrict__ S) {
  __shared__ __align__(16) float sPq[8][NU_];
  __shared__ __align__(16) float sV[NU_];
  int b = blockIdx.x >> 3, qt = blockIdx.x & 7, kt = blockIdx.y;
  int q0 = qt * 8, k0 = kt * 64;
  int t = threadIdx.x;
  const float4* pqsrc =
      reinterpret_cast<const float4*>(pq + ((size_t)b * Q_ + q0) * NU_);
#pragma unroll
  for (int i = 0; i < 4; i++)
    reinterpret_cast<float4*>(&sPq[0][0])[t + 256 * i] = pqsrc[t + 256 * i];
  if (t < 128)
    reinterpret_cast<float4*>(sV)[t] = reinterpret_cast<const float4*>(v)[t];
  __syncthreads();

  int wave = t >> 6, lane = t & 63;
  int ksub = lane >> 2, ulane = lane & 3;
  int k = k0 + wave * 16 + ksub;
  const float* pkr = pk + ((size_t)b * K_ + k) * NU_;
  float acc[8] = {};
  const float C2 = 2.8853900817779268f;  // 2*log2(e)
#pragma unroll 4
  for (int j = 0; j < 32; j++) {
    int u = j * 16 + ulane * 4;
    float4 pk4 = *reinterpret_cast<const float4*>(&pkr[u]);
    float4 v4 = *reinterpret_cast<const float4*>(&sV[u]);
    float pkv[4] = {pk4.x, pk4.y, pk4.z, pk4.w};
    float vv[4] = {v4.x, v4.y, v4.z, v4.w};
#pragma unroll
    for (int qq = 0; qq < 8; qq++) {
      float4 pq4 = *reinterpret_cast<const float4*>(&sPq[qq][u]);
      float pqv[4] = {pq4.x, pq4.y, pq4.z, pq4.w};
#pragma unroll
      for (int i = 0; i < 4; i++) {
        float e = __builtin_amdgcn_exp2f((pkv[i] + pqv[i]) * C2);
        float r = __builtin_amdgcn_rcpf(1.f + e);
        acc[qq] = fmaf(vv[i], fmaf(-2.f, r, 1.f), acc[qq]);
      }
    }
  }
#pragma unroll
  for (int qq = 0; qq < 8; qq++) {
    float a = acc[qq];
    a += __shfl_xor(a, 1, 64);
    a += __shfl_xor(a, 2, 64);
    if (ulane == 0) S[((size_t)b * Q_ + q0 + qq) * K_ + k] = a;
  }
}

// ---------------------------------------------------------------------------
// Kernel 4: softmax (dt==0 blocks) + context.
// ---------------------------------------------------------------------------
__global__ __launch_bounds__(256) void ctx_kernel(
    const float* __restrict__ S, const float* __restrict__ keys,
    float* __restrict__ ctx, float* __restrict__ smx) {
  __shared__ __align__(16) float sS[8][K_];
  __shared__ __align__(16) float sK[64][64];
  int b = blockIdx.x >> 3, qt = blockIdx.x & 7, dt = blockIdx.y;
  int q0 = qt * 8, d0 = dt * 64;
  int t = threadIdx.x;
  const float4* ssrc =
      reinterpret_cast<const float4*>(S + ((size_t)b * Q_ + q0) * K_);
#pragma unroll
  for (int i = 0; i < 4; i++)
    reinterpret_cast<float4*>(&sS[0][0])[t + 256 * i] = ssrc[t + 256 * i];
  __syncthreads();

  int q = t >> 5, lg = t & 31;
  float m = -1e30f;
  for (int kk = lg; kk < K_; kk += 32) m = fmaxf(m, sS[q][kk]);
#pragma unroll
  for (int o = 1; o < 32; o <<= 1) m = fmaxf(m, __shfl_xor(m, o, 64));
  const float L2E = 1.4426950408889634f;
  float sum = 0.f;
  for (int kk = lg; kk < K_; kk += 32)
    sum += __builtin_amdgcn_exp2f((sS[q][kk] - m) * L2E);
#pragma unroll
  for (int o = 1; o < 32; o <<= 1) sum += __shfl_xor(sum, o, 64);
  if (dt == 0) {
    float inv = 1.f / sum;
    float* dst = smx + ((size_t)b * Q_ + q0 + q) * K_;
    for (int kk = lg; kk < K_; kk += 32)
      dst[kk] = __builtin_amdgcn_exp2f((sS[q][kk] - m) * L2E) * inv;
  }

  float c0 = 0.f, c1 = 0.f;
  const float* keysb = keys + (size_t)b * K_ * D_ + d0;
  for (int kc = 0; kc < K_; kc += 64) {
    __syncthreads();
    for (int i = t; i < 64 * 16; i += 256) {
      int row = i >> 4, c4 = i & 15;
      reinterpret_cast<float4*>(&sK[row][0])[c4] =
          *reinterpret_cast<const float4*>(
              &keysb[(size_t)(kc + row) * D_ + c4 * 4]);
    }
    __syncthreads();
#pragma unroll 8
    for (int kk = 0; kk < 64; kk++) {
      float s = sS[q][kc + kk];
      float2 kv = *reinterpret_cast<const float2*>(&sK[kk][lg * 2]);
      c0 = fmaf(s, kv.x, c0);
      c1 = fmaf(s, kv.y, c1);
    }
  }
  float2 o2 = {c0, c1};
  *reinterpret_cast<float2*>(
      &ctx[((size_t)b * Q_ + q0 + q) * D_ + d0 + lg * 2]) = o2;
}

// ---------------------------------------------------------------------------
extern "C" void kernel_launch(void* const* d_in, const int* in_sizes, int n_in,
                              void* d_out, int out_size, void* d_ws,
                              size_t ws_size, hipStream_t stream) {
  const float* query = (const float*)d_in[0];
  const float* keys = (const float*)d_in[1];
  const float* Wq = (const float*)d_in[2];
  const float* Wk = (const float*)d_in[3];
  const float* la = (const float*)d_in[4];
  const float* nscalar = (const float*)d_in[5];
  const float* nbias = (const float*)d_in[6];

  float* out = (float*)d_out;
  float* ctx = out;
  float* smx = out + (size_t)B_ * Q_ * D_;

  float* ws = (float*)d_ws;
  float* v = ws + WS_V;
  float* pq = ws + WS_PQ;
  float* pk = ws + WS_PK;
  float* S = ws + WS_S;

  if (ws_size >= (size_t)WS_BYTES_MFMA) {
    _Float16* Ah = (_Float16*)(ws + WS_FLOATS);
    _Float16* Wkh = Ah + AH_ELEMS;
    _Float16* Wqh = Wkh + WH_ELEMS;
    convert_kernel<<<CONV_BLOCKS + 1, 256, 0, stream>>>(
        query, keys, Wq, Wk, la, nscalar, Ah, Wkh, Wqh, v);
    mfma_proj_kernel<<<dim3(72, 8), 256, 0, stream>>>(Ah, Wkh, Wqh, nbias, pk,
                                                      pq);
  } else {
    compute_v_kernel<<<1, 512, 0, stream>>>(la, nscalar, v);
    proj_gemm_kernel<<<dim3(72, 8), 256, 0, stream>>>(query, keys, Wq, Wk,
                                                      nbias, pq, pk);
  }
  scores_kernel<<<dim3(64, 8), 256, 0, stream>>>(pq, pk, v, S);
  ctx_kernel<<<dim3(64, 8), 256, 0, stream>>>(S, keys, ctx, smx);
}

// Round 4
// 61.877 us; speedup vs baseline: 3.1570x; 1.4034x over previous
//
#include <hip/hip_runtime.h>

#define B_ 8
#define Q_ 64
#define K_ 512
#define NU_ 512
#define D_ 512

typedef __attribute__((ext_vector_type(8))) _Float16 half8;
typedef __attribute__((ext_vector_type(4))) _Float16 half4;
typedef __attribute__((ext_vector_type(16))) float floatx16;

#define C2F 2.8853900817779268f  // 2*log2(e)

// ws float-layout
#define WS_V 0                      // v[0..511], vtot at [512]
#define WS_EQ 640                   // Eq: 8*64*512
#define WS_EK (640 + 262144)        // Ek: 8*512*512
#define WS_S (WS_EK + 2097152)      // S raw scores: 8*64*512
#define WS_FLOATS (WS_S + 262144)   // = 2622080 floats
#define AH_ELEMS 2359296            // 4608*512 f16 (keys rows 0..4095, query 4096..4607)
#define WH_ELEMS 262144             // 512*512 f16
#define WS_BYTES_MFMA (WS_FLOATS * 4 + (size_t)(AH_ELEMS + 2 * WH_ELEMS) * 2)

// ---------------------------------------------------------------------------
// Kernel 1: fused f32->f16 conversion + v-normalize (+ vtot).
// ---------------------------------------------------------------------------
#define CHUNKS_KEYS 524288
#define CHUNKS_Q 65536
#define CHUNKS_W 65536
#define CONV_BLOCKS 2816

__global__ __launch_bounds__(256) void convert_kernel(
    const float* __restrict__ query, const float* __restrict__ keys,
    const float* __restrict__ Wq, const float* __restrict__ Wk,
    const float* __restrict__ la, const float* __restrict__ scalar,
    _Float16* __restrict__ Ah, _Float16* __restrict__ Wkh,
    _Float16* __restrict__ Wqh, float* __restrict__ v) {
  int bid = blockIdx.x;
  int t = threadIdx.x;
  if (bid == CONV_BLOCKS) {
    __shared__ float red[4], red2[4];
    float x0 = la[t], x1 = la[t + 256];
    float ss = x0 * x0 + x1 * x1;
#pragma unroll
    for (int o = 1; o < 64; o <<= 1) ss += __shfl_xor(ss, o, 64);
    int wave = t >> 6, lane = t & 63;
    if (lane == 0) red[wave] = ss;
    __syncthreads();
    float tot = red[0] + red[1] + red[2] + red[3];
    float sc = rsqrtf(tot) * scalar[0];
    float v0 = x0 * sc, v1 = x1 * sc;
    v[t] = v0;
    v[t + 256] = v1;
    float sv = v0 + v1;
#pragma unroll
    for (int o = 1; o < 64; o <<= 1) sv += __shfl_xor(sv, o, 64);
    if (lane == 0) red2[wave] = sv;
    __syncthreads();
    if (t == 0) v[512] = red2[0] + red2[1] + red2[2] + red2[3];
    return;
  }
  int c = bid * 256 + t;
  const float* src;
  _Float16* dst;
  if (c < CHUNKS_KEYS) {
    src = keys;
    dst = Ah;
  } else if (c < CHUNKS_KEYS + CHUNKS_Q) {
    src = query;
    dst = Ah + 2097152;
    c -= CHUNKS_KEYS;
  } else if (c < CHUNKS_KEYS + CHUNKS_Q + CHUNKS_W) {
    src = Wk;
    dst = Wkh;
    c -= CHUNKS_KEYS + CHUNKS_Q;
  } else {
    src = Wq;
    dst = Wqh;
    c -= CHUNKS_KEYS + CHUNKS_Q + CHUNKS_W;
  }
  float4 x = reinterpret_cast<const float4*>(src)[c];
  half4 o = {(_Float16)x.x, (_Float16)x.y, (_Float16)x.z, (_Float16)x.w};
  *reinterpret_cast<half4*>(dst + (size_t)c * 4) = o;
}

// ---------------------------------------------------------------------------
// Kernel 2: MFMA projection; epilogue writes Eq=2^(C2*(pq+bias)), Ek=2^(C2*pk)
// ---------------------------------------------------------------------------
__global__ __launch_bounds__(256) void mfma_proj_kernel(
    const _Float16* __restrict__ Ah, const _Float16* __restrict__ Wkh,
    const _Float16* __restrict__ Wqh, const float* __restrict__ bias,
    float* __restrict__ Ek, float* __restrict__ Eq) {
  __shared__ _Float16 sA[64][40];
  __shared__ _Float16 sW[64][40];
  int m0 = blockIdx.x * 64, n0 = blockIdx.y * 64;
  bool isQ = (m0 >= 4096);
  const _Float16* W = isQ ? Wqh : Wkh;
  int t = threadIdx.x;
  int crow = t >> 2, cq = t & 3;
  const _Float16* gA = Ah + (size_t)(m0 + crow) * 512 + cq * 8;
  const _Float16* gW = W + (size_t)(n0 + crow) * 512 + cq * 8;
  _Float16* lA = &sA[crow][cq * 8];
  _Float16* lW = &sW[crow][cq * 8];
  int wave = t >> 6, lane = t & 63;
  int mw = (wave >> 1) * 32, nw = (wave & 1) * 32;
  int lr = lane & 31, g = lane >> 5;
  const _Float16* rdA0 = &sA[mw + lr][g * 8];
  const _Float16* rdA1 = &sA[mw + lr][16 + g * 8];
  const _Float16* rdW0 = &sW[nw + lr][g * 8];
  const _Float16* rdW1 = &sW[nw + lr][16 + g * 8];
  floatx16 acc;
#pragma unroll
  for (int i = 0; i < 16; i++) acc[i] = 0.f;
  for (int k0 = 0; k0 < 512; k0 += 32) {
    half8 va = *reinterpret_cast<const half8*>(gA + k0);
    half8 vw = *reinterpret_cast<const half8*>(gW + k0);
    __syncthreads();
    *reinterpret_cast<half8*>(lA) = va;
    *reinterpret_cast<half8*>(lW) = vw;
    __syncthreads();
    half8 a0 = *reinterpret_cast<const half8*>(rdA0);
    half8 a1 = *reinterpret_cast<const half8*>(rdA1);
    half8 w0 = *reinterpret_cast<const half8*>(rdW0);
    half8 w1 = *reinterpret_cast<const half8*>(rdW1);
    acc = __builtin_amdgcn_mfma_f32_32x32x16_f16(a0, w0, acc, 0, 0, 0);
    acc = __builtin_amdgcn_mfma_f32_32x32x16_f16(a1, w1, acc, 0, 0, 0);
  }
  int col = n0 + nw + lr;
  float bv = isQ ? bias[col] : 0.f;
#pragma unroll
  for (int r = 0; r < 16; r++) {
    int mrow = m0 + mw + (r & 3) + 8 * (r >> 2) + 4 * g;
    float e = __builtin_amdgcn_exp2f((acc[r] + bv) * C2F);
    if (isQ)
      Eq[(size_t)(mrow - 4096) * NU_ + col] = e;
    else
      Ek[(size_t)mrow * NU_ + col] = e;
  }
}

// ---------------------------------------------------------------------------
// Fallback (ws too small): f32 projection writing Eq/Ek, + v kernel
// ---------------------------------------------------------------------------
__global__ __launch_bounds__(512) void compute_v_kernel(
    const float* __restrict__ la, const float* __restrict__ scalar,
    float* __restrict__ v) {
  __shared__ float red[8], red2[8];
  int t = threadIdx.x;
  float x = la[t];
  float ss = x * x;
#pragma unroll
  for (int o = 1; o < 64; o <<= 1) ss += __shfl_xor(ss, o, 64);
  int wave = t >> 6, lane = t & 63;
  if (lane == 0) red[wave] = ss;
  __syncthreads();
  float tot = 0.f;
#pragma unroll
  for (int w = 0; w < 8; w++) tot += red[w];
  float vv = x * rsqrtf(tot) * scalar[0];
  v[t] = vv;
  float sv = vv;
#pragma unroll
  for (int o = 1; o < 64; o <<= 1) sv += __shfl_xor(sv, o, 64);
  if (lane == 0) red2[wave] = sv;
  __syncthreads();
  if (t == 0) {
    float s = 0.f;
#pragma unroll
    for (int w = 0; w < 8; w++) s += red2[w];
    v[512] = s;
  }
}

__global__ __launch_bounds__(256) void proj_gemm_kernel(
    const float* __restrict__ query, const float* __restrict__ keys,
    const float* __restrict__ Wq, const float* __restrict__ Wk,
    const float* __restrict__ bias, float* __restrict__ Eq,
    float* __restrict__ Ek) {
  __shared__ __align__(16) float As[16][68];
  __shared__ __align__(16) float Bs[16][68];
  int mt = blockIdx.x;
  int n0 = blockIdx.y * 64;
  const float* A;
  const float* W;
  float* C;
  bool ub;
  if (mt < 8) {
    A = query + (size_t)mt * 64 * D_;
    W = Wq;
    C = Eq + (size_t)mt * 64 * NU_;
    ub = true;
  } else {
    A = keys + (size_t)(mt - 8) * 64 * D_;
    W = Wk;
    C = Ek + (size_t)(mt - 8) * 64 * NU_;
    ub = false;
  }
  int t = threadIdx.x;
  int tx = t & 15, ty = t >> 4;
  int ld = t & 15, lm = t >> 4;
  float acc[4][4] = {};
  for (int d0 = 0; d0 < D_; d0 += 16) {
#pragma unroll
    for (int r = 0; r < 4; r++) {
      As[ld][lm + 16 * r] = A[(size_t)(lm + 16 * r) * D_ + d0 + ld];
      Bs[ld][lm + 16 * r] = W[(size_t)(n0 + lm + 16 * r) * D_ + d0 + ld];
    }
    __syncthreads();
#pragma unroll
    for (int dd = 0; dd < 16; dd++) {
      float4 a4 = *reinterpret_cast<const float4*>(&As[dd][ty * 4]);
      float4 b4 = *reinterpret_cast<const float4*>(&Bs[dd][tx * 4]);
      float av[4] = {a4.x, a4.y, a4.z, a4.w};
      float bv[4] = {b4.x, b4.y, b4.z, b4.w};
#pragma unroll
      for (int i = 0; i < 4; i++)
#pragma unroll
        for (int j = 0; j < 4; j++)
          acc[i][j] = fmaf(av[i], bv[j], acc[i][j]);
    }
    __syncthreads();
  }
#pragma unroll
  for (int i = 0; i < 4; i++) {
    float4 o;
    float* op = &o.x;
#pragma unroll
    for (int j = 0; j < 4; j++) {
      float val = acc[i][j];
      if (ub) val += bias[n0 + tx * 4 + j];
      op[j] = __builtin_amdgcn_exp2f(val * C2F);
    }
    *reinterpret_cast<float4*>(&C[(size_t)(ty * 4 + i) * NU_ + n0 + tx * 4]) = o;
  }
}

// ---------------------------------------------------------------------------
// Kernel 3: scores. Block = (b, qtile 8, ktile 32). 256 thr, wave = 8k x 8u.
// S[q,k] = vtot - 2 * sum_u v[u] / (1 + Eq[q,u]*Ek[k,u])
// ---------------------------------------------------------------------------
__global__ __launch_bounds__(256) void scores_kernel(
    const float* __restrict__ Eq, const float* __restrict__ Ek,
    const float* __restrict__ v, float* __restrict__ S) {
  __shared__ __align__(16) float sEq[8][NU_];  // 16 KB
  __shared__ __align__(16) float sV[NU_];      // 2 KB
  int b = blockIdx.x >> 3, qt = blockIdx.x & 7, kt = blockIdx.y;
  int q0 = qt * 8, k0 = kt * 32;
  int t = threadIdx.x;
  const float4* eqsrc =
      reinterpret_cast<const float4*>(Eq + ((size_t)b * Q_ + q0) * NU_);
#pragma unroll
  for (int i = 0; i < 4; i++)
    reinterpret_cast<float4*>(&sEq[0][0])[t + 256 * i] = eqsrc[t + 256 * i];
  if (t < 128)
    reinterpret_cast<float4*>(sV)[t] = reinterpret_cast<const float4*>(v)[t];
  float vtot = v[512];
  __syncthreads();

  int wave = t >> 6, lane = t & 63;
  int ksub = lane >> 3, ulane = lane & 7;
  int k = k0 + wave * 8 + ksub;
  const float* ekr = Ek + ((size_t)b * K_ + k) * NU_;
  float acc[8] = {};
#pragma unroll 2
  for (int j = 0; j < 16; j++) {
    int u = ulane * 4 + 32 * j;
    float4 ek4 = *reinterpret_cast<const float4*>(&ekr[u]);
    float4 v4 = *reinterpret_cast<const float4*>(&sV[u]);
    float ekv[4] = {ek4.x, ek4.y, ek4.z, ek4.w};
    float vv[4] = {v4.x, v4.y, v4.z, v4.w};
#pragma unroll
    for (int qq = 0; qq < 8; qq++) {
      float4 eq4 = *reinterpret_cast<const float4*>(&sEq[qq][u]);
      float eqv[4] = {eq4.x, eq4.y, eq4.z, eq4.w};
#pragma unroll
      for (int i = 0; i < 4; i++) {
        float d = fmaf(eqv[i], ekv[i], 1.f);
        float r = __builtin_amdgcn_rcpf(d);
        acc[qq] = fmaf(vv[i], r, acc[qq]);
      }
    }
  }
#pragma unroll
  for (int qq = 0; qq < 8; qq++) {
    float a = acc[qq];
    a += __shfl_xor(a, 1, 64);
    a += __shfl_xor(a, 2, 64);
    a += __shfl_xor(a, 4, 64);
    if (ulane == 0)
      S[((size_t)b * Q_ + q0 + qq) * K_ + k] = fmaf(-2.f, a, vtot);
  }
}

// ---------------------------------------------------------------------------
// Kernel 4: softmax (dt==0) + context, double-buffered keys chunks.
// ---------------------------------------------------------------------------
__global__ __launch_bounds__(256) void ctx_kernel(
    const float* __restrict__ S, const float* __restrict__ keys,
    float* __restrict__ ctx, float* __restrict__ smx) {
  __shared__ __align__(16) float sS[8][K_];       // 16 KB
  __shared__ __align__(16) float sK[2][64][64];   // 32 KB
  int b = blockIdx.x >> 3, qt = blockIdx.x & 7, dt = blockIdx.y;
  int q0 = qt * 8, d0 = dt * 64;
  int t = threadIdx.x;
  const float4* ssrc =
      reinterpret_cast<const float4*>(S + ((size_t)b * Q_ + q0) * K_);
#pragma unroll
  for (int i = 0; i < 4; i++)
    reinterpret_cast<float4*>(&sS[0][0])[t + 256 * i] = ssrc[t + 256 * i];
  const float* keysb = keys + (size_t)b * K_ * D_ + d0;
#pragma unroll
  for (int i = t; i < 1024; i += 256) {
    int row = i >> 4, c4 = i & 15;
    reinterpret_cast<float4*>(&sK[0][row][0])[c4] =
        *reinterpret_cast<const float4*>(&keysb[(size_t)row * D_ + c4 * 4]);
  }
  __syncthreads();

  int q = t >> 5, lg = t & 31;
  float m = -1e30f;
  for (int kk = lg; kk < K_; kk += 32) m = fmaxf(m, sS[q][kk]);
#pragma unroll
  for (int o = 1; o < 32; o <<= 1) m = fmaxf(m, __shfl_xor(m, o, 64));
  const float L2E = 1.4426950408889634f;
  float sum = 0.f;
  for (int kk = lg; kk < K_; kk += 32)
    sum += __builtin_amdgcn_exp2f((sS[q][kk] - m) * L2E);
#pragma unroll
  for (int o = 1; o < 32; o <<= 1) sum += __shfl_xor(sum, o, 64);
  if (dt == 0) {
    float inv = 1.f / sum;
    float* dst = smx + ((size_t)b * Q_ + q0 + q) * K_;
    for (int kk = lg; kk < K_; kk += 32)
      dst[kk] = __builtin_amdgcn_exp2f((sS[q][kk] - m) * L2E) * inv;
  }

  int cur = 0;
  float c00 = 0.f, c01 = 0.f, c10 = 0.f, c11 = 0.f;
  for (int kc = 0; kc < K_; kc += 64) {
    if (kc + 64 < K_) {
      const float* kn = keysb + (size_t)(kc + 64) * D_;
      for (int i = t; i < 1024; i += 256) {
        int row = i >> 4, c4 = i & 15;
        reinterpret_cast<float4*>(&sK[cur ^ 1][row][0])[c4] =
            *reinterpret_cast<const float4*>(&kn[(size_t)row * D_ + c4 * 4]);
      }
    }
#pragma unroll 8
    for (int kk = 0; kk < 32; kk++) {
      float s0 = sS[q][kc + kk];
      float2 kv0 = *reinterpret_cast<const float2*>(&sK[cur][kk][lg * 2]);
      c00 = fmaf(s0, kv0.x, c00);
      c01 = fmaf(s0, kv0.y, c01);
      float s1 = sS[q][kc + 32 + kk];
      float2 kv1 = *reinterpret_cast<const float2*>(&sK[cur][32 + kk][lg * 2]);
      c10 = fmaf(s1, kv1.x, c10);
      c11 = fmaf(s1, kv1.y, c11);
    }
    __syncthreads();
    cur ^= 1;
  }
  float2 o2 = {c00 + c10, c01 + c11};
  *reinterpret_cast<float2*>(
      &ctx[((size_t)b * Q_ + q0 + q) * D_ + d0 + lg * 2]) = o2;
}

// ---------------------------------------------------------------------------
extern "C" void kernel_launch(void* const* d_in, const int* in_sizes, int n_in,
                              void* d_out, int out_size, void* d_ws,
                              size_t ws_size, hipStream_t stream) {
  const float* query = (const float*)d_in[0];
  const float* keys = (const float*)d_in[1];
  const float* Wq = (const float*)d_in[2];
  const float* Wk = (const float*)d_in[3];
  const float* la = (const float*)d_in[4];
  const float* nscalar = (const float*)d_in[5];
  const float* nbias = (const float*)d_in[6];

  float* out = (float*)d_out;
  float* ctx = out;
  float* smx = out + (size_t)B_ * Q_ * D_;

  float* ws = (float*)d_ws;
  float* v = ws + WS_V;
  float* Eq = ws + WS_EQ;
  float* Ek = ws + WS_EK;
  float* S = ws + WS_S;

  if (ws_size >= (size_t)WS_BYTES_MFMA) {
    _Float16* Ah = (_Float16*)(ws + WS_FLOATS);
    _Float16* Wkh = Ah + AH_ELEMS;
    _Float16* Wqh = Wkh + WH_ELEMS;
    convert_kernel<<<CONV_BLOCKS + 1, 256, 0, stream>>>(
        query, keys, Wq, Wk, la, nscalar, Ah, Wkh, Wqh, v);
    mfma_proj_kernel<<<dim3(72, 8), 256, 0, stream>>>(Ah, Wkh, Wqh, nbias, Ek,
                                                      Eq);
  } else {
    compute_v_kernel<<<1, 512, 0, stream>>>(la, nscalar, v);
    proj_gemm_kernel<<<dim3(72, 8), 256, 0, stream>>>(query, keys, Wq, Wk,
                                                      nbias, Eq, Ek);
  }
  scores_kernel<<<dim3(64, 16), 256, 0, stream>>>(Eq, Ek, v, S);
  ctx_kernel<<<dim3(64, 8), 256, 0, stream>>>(S, keys, ctx, smx);
}

// Round 5
// 56.706 us; speedup vs baseline: 3.4449x; 1.0912x over previous
//
#include <hip/hip_runtime.h>

#define B_ 8
#define Q_ 64
#define K_ 512
#define NU_ 512
#define D_ 512

typedef __attribute__((ext_vector_type(8))) _Float16 half8;
typedef __attribute__((ext_vector_type(4))) _Float16 half4;
typedef __attribute__((ext_vector_type(16))) float floatx16;

#define C2F 2.8853900817779268f  // 2*log2(e)

// ws float-layout
#define WS_V 0                      // v[0..511], vtot at [512]
#define WS_EQ 640                   // Eq: 8*64*512
#define WS_EK (640 + 262144)        // Ek: 8*512*512
#define WS_S (WS_EK + 2097152)      // S raw scores: 8*64*512
#define WS_FLOATS (WS_S + 262144)
#define AH_ELEMS 2359296            // 4608*512 f16 (keys rows 0..4095, query 4096..4607)
#define WH_ELEMS 262144             // 512*512 f16
#define WS_BYTES_MFMA (WS_FLOATS * 4 + (size_t)(AH_ELEMS + 2 * WH_ELEMS) * 2)

// ---------------------------------------------------------------------------
// Kernel 1: fused f32->f16 conversion + v-normalize (+ vtot at v[512]).
// ---------------------------------------------------------------------------
#define CHUNKS_KEYS 524288
#define CHUNKS_Q 65536
#define CHUNKS_W 65536
#define CONV_BLOCKS 2816

__global__ __launch_bounds__(256) void convert_kernel(
    const float* __restrict__ query, const float* __restrict__ keys,
    const float* __restrict__ Wq, const float* __restrict__ Wk,
    const float* __restrict__ la, const float* __restrict__ scalar,
    _Float16* __restrict__ Ah, _Float16* __restrict__ Wkh,
    _Float16* __restrict__ Wqh, float* __restrict__ v) {
  int bid = blockIdx.x;
  int t = threadIdx.x;
  if (bid == CONV_BLOCKS) {
    __shared__ float red[4], red2[4];
    float x0 = la[t], x1 = la[t + 256];
    float ss = x0 * x0 + x1 * x1;
#pragma unroll
    for (int o = 1; o < 64; o <<= 1) ss += __shfl_xor(ss, o, 64);
    int wave = t >> 6, lane = t & 63;
    if (lane == 0) red[wave] = ss;
    __syncthreads();
    float tot = red[0] + red[1] + red[2] + red[3];
    float sc = rsqrtf(tot) * scalar[0];
    float v0 = x0 * sc, v1 = x1 * sc;
    v[t] = v0;
    v[t + 256] = v1;
    float sv = v0 + v1;
#pragma unroll
    for (int o = 1; o < 64; o <<= 1) sv += __shfl_xor(sv, o, 64);
    if (lane == 0) red2[wave] = sv;
    __syncthreads();
    if (t == 0) v[512] = red2[0] + red2[1] + red2[2] + red2[3];
    return;
  }
  int c = bid * 256 + t;
  const float* src;
  _Float16* dst;
  if (c < CHUNKS_KEYS) {
    src = keys;
    dst = Ah;
  } else if (c < CHUNKS_KEYS + CHUNKS_Q) {
    src = query;
    dst = Ah + 2097152;
    c -= CHUNKS_KEYS;
  } else if (c < CHUNKS_KEYS + CHUNKS_Q + CHUNKS_W) {
    src = Wk;
    dst = Wkh;
    c -= CHUNKS_KEYS + CHUNKS_Q;
  } else {
    src = Wq;
    dst = Wqh;
    c -= CHUNKS_KEYS + CHUNKS_Q + CHUNKS_W;
  }
  float4 x = reinterpret_cast<const float4*>(src)[c];
  half4 o = {(_Float16)x.x, (_Float16)x.y, (_Float16)x.z, (_Float16)x.w};
  *reinterpret_cast<half4*>(dst + (size_t)c * 4) = o;
}

// ---------------------------------------------------------------------------
// Kernel 2: MFMA projection, K_STEP=64, prefetched staging.
// Epilogue writes Eq=2^(C2*(pq+bias)), Ek=2^(C2*pk).
// ---------------------------------------------------------------------------
__global__ __launch_bounds__(256) void mfma_proj_kernel(
    const _Float16* __restrict__ Ah, const _Float16* __restrict__ Wkh,
    const _Float16* __restrict__ Wqh, const float* __restrict__ bias,
    float* __restrict__ Ek, float* __restrict__ Eq) {
  __shared__ _Float16 sA[64][72];  // 144B row stride, 16B aligned
  __shared__ _Float16 sW[64][72];
  int m0 = blockIdx.x * 64, n0 = blockIdx.y * 64;
  bool isQ = (m0 >= 4096);
  const _Float16* W = isQ ? Wqh : Wkh;
  int t = threadIdx.x;
  // staging: thread owns 32B (two half8) of one row per matrix per K-step
  int srow = t >> 2, soff = (t & 3) * 16;
  const _Float16* gA = Ah + (size_t)(m0 + srow) * 512 + soff;
  const _Float16* gW = W + (size_t)(n0 + srow) * 512 + soff;
  _Float16* lA = &sA[srow][soff];
  _Float16* lW = &sW[srow][soff];
  int wave = t >> 6, lane = t & 63;
  int mw = (wave >> 1) * 32, nw = (wave & 1) * 32;
  int lr = lane & 31, g = lane >> 5;
  half8 pa0 = *reinterpret_cast<const half8*>(gA);
  half8 pa1 = *reinterpret_cast<const half8*>(gA + 8);
  half8 pw0 = *reinterpret_cast<const half8*>(gW);
  half8 pw1 = *reinterpret_cast<const half8*>(gW + 8);
  floatx16 acc;
#pragma unroll
  for (int i = 0; i < 16; i++) acc[i] = 0.f;
  for (int k0 = 0; k0 < 512; k0 += 64) {
    __syncthreads();  // previous iteration's fragment reads complete
    *reinterpret_cast<half8*>(lA) = pa0;
    *reinterpret_cast<half8*>(lA + 8) = pa1;
    *reinterpret_cast<half8*>(lW) = pw0;
    *reinterpret_cast<half8*>(lW + 8) = pw1;
    if (k0 + 64 < 512) {
      pa0 = *reinterpret_cast<const half8*>(gA + k0 + 64);
      pa1 = *reinterpret_cast<const half8*>(gA + k0 + 72);
      pw0 = *reinterpret_cast<const half8*>(gW + k0 + 64);
      pw1 = *reinterpret_cast<const half8*>(gW + k0 + 72);
    }
    __syncthreads();  // LDS ready
#pragma unroll
    for (int i = 0; i < 4; i++) {
      half8 af = *reinterpret_cast<const half8*>(&sA[mw + lr][i * 16 + g * 8]);
      half8 wf = *reinterpret_cast<const half8*>(&sW[nw + lr][i * 16 + g * 8]);
      acc = __builtin_amdgcn_mfma_f32_32x32x16_f16(af, wf, acc, 0, 0, 0);
    }
  }
  int col = n0 + nw + lr;
  float bv = isQ ? bias[col] : 0.f;
#pragma unroll
  for (int r = 0; r < 16; r++) {
    int mrow = m0 + mw + (r & 3) + 8 * (r >> 2) + 4 * g;
    float e = __builtin_amdgcn_exp2f((acc[r] + bv) * C2F);
    if (isQ)
      Eq[(size_t)(mrow - 4096) * NU_ + col] = e;
    else
      Ek[(size_t)mrow * NU_ + col] = e;
  }
}

// ---------------------------------------------------------------------------
// Fallback (ws too small): f32 projection writing Eq/Ek, + v kernel
// ---------------------------------------------------------------------------
__global__ __launch_bounds__(512) void compute_v_kernel(
    const float* __restrict__ la, const float* __restrict__ scalar,
    float* __restrict__ v) {
  __shared__ float red[8], red2[8];
  int t = threadIdx.x;
  float x = la[t];
  float ss = x * x;
#pragma unroll
  for (int o = 1; o < 64; o <<= 1) ss += __shfl_xor(ss, o, 64);
  int wave = t >> 6, lane = t & 63;
  if (lane == 0) red[wave] = ss;
  __syncthreads();
  float tot = 0.f;
#pragma unroll
  for (int w = 0; w < 8; w++) tot += red[w];
  float vv = x * rsqrtf(tot) * scalar[0];
  v[t] = vv;
  float sv = vv;
#pragma unroll
  for (int o = 1; o < 64; o <<= 1) sv += __shfl_xor(sv, o, 64);
  if (lane == 0) red2[wave] = sv;
  __syncthreads();
  if (t == 0) {
    float s = 0.f;
#pragma unroll
    for (int w = 0; w < 8; w++) s += red2[w];
    v[512] = s;
  }
}

__global__ __launch_bounds__(256) void proj_gemm_kernel(
    const float* __restrict__ query, const float* __restrict__ keys,
    const float* __restrict__ Wq, const float* __restrict__ Wk,
    const float* __restrict__ bias, float* __restrict__ Eq,
    float* __restrict__ Ek) {
  __shared__ __align__(16) float As[16][68];
  __shared__ __align__(16) float Bs[16][68];
  int mt = blockIdx.x;
  int n0 = blockIdx.y * 64;
  const float* A;
  const float* W;
  float* C;
  bool ub;
  if (mt < 8) {
    A = query + (size_t)mt * 64 * D_;
    W = Wq;
    C = Eq + (size_t)mt * 64 * NU_;
    ub = true;
  } else {
    A = keys + (size_t)(mt - 8) * 64 * D_;
    W = Wk;
    C = Ek + (size_t)(mt - 8) * 64 * NU_;
    ub = false;
  }
  int t = threadIdx.x;
  int tx = t & 15, ty = t >> 4;
  int ld = t & 15, lm = t >> 4;
  float acc[4][4] = {};
  for (int d0 = 0; d0 < D_; d0 += 16) {
#pragma unroll
    for (int r = 0; r < 4; r++) {
      As[ld][lm + 16 * r] = A[(size_t)(lm + 16 * r) * D_ + d0 + ld];
      Bs[ld][lm + 16 * r] = W[(size_t)(n0 + lm + 16 * r) * D_ + d0 + ld];
    }
    __syncthreads();
#pragma unroll
    for (int dd = 0; dd < 16; dd++) {
      float4 a4 = *reinterpret_cast<const float4*>(&As[dd][ty * 4]);
      float4 b4 = *reinterpret_cast<const float4*>(&Bs[dd][tx * 4]);
      float av[4] = {a4.x, a4.y, a4.z, a4.w};
      float bv[4] = {b4.x, b4.y, b4.z, b4.w};
#pragma unroll
      for (int i = 0; i < 4; i++)
#pragma unroll
        for (int j = 0; j < 4; j++)
          acc[i][j] = fmaf(av[i], bv[j], acc[i][j]);
    }
    __syncthreads();
  }
#pragma unroll
  for (int i = 0; i < 4; i++) {
    float4 o;
    float* op = &o.x;
#pragma unroll
    for (int j = 0; j < 4; j++) {
      float val = acc[i][j];
      if (ub) val += bias[n0 + tx * 4 + j];
      op[j] = __builtin_amdgcn_exp2f(val * C2F);
    }
    *reinterpret_cast<float4*>(&C[(size_t)(ty * 4 + i) * NU_ + n0 + tx * 4]) = o;
  }
}

// ---------------------------------------------------------------------------
// Kernel 3: scores. Block = (b, qtile 8, ktile 32). 256 thr.
// Wave pairs split u; each lane: 8 q x 2 k accumulators, 4-u slice.
// S[q,k] = vtot - 2 * sum_u v[u] / (1 + Eq[q,u]*Ek[k,u])
// ---------------------------------------------------------------------------
__global__ __launch_bounds__(256) void scores_kernel(
    const float* __restrict__ Eq, const float* __restrict__ Ek,
    const float* __restrict__ v, float* __restrict__ S) {
  __shared__ __align__(16) float sEq[8][NU_];  // 16 KB
  __shared__ __align__(16) float sV[NU_];      // 2 KB
  __shared__ float sRed[2][8][8][2];           // uw==1 partials: 1 KB
  int b = blockIdx.x >> 3, qt = blockIdx.x & 7, kt = blockIdx.y;
  int q0 = qt * 8, k0 = kt * 32;
  int t = threadIdx.x;
  const float4* eqsrc =
      reinterpret_cast<const float4*>(Eq + ((size_t)b * Q_ + q0) * NU_);
#pragma unroll
  for (int i = 0; i < 4; i++)
    reinterpret_cast<float4*>(&sEq[0][0])[t + 256 * i] = eqsrc[t + 256 * i];
  if (t < 128)
    reinterpret_cast<float4*>(sV)[t] = reinterpret_cast<const float4*>(v)[t];
  float vtot = v[512];
  __syncthreads();

  int wave = t >> 6, lane = t & 63;
  int uw = wave >> 1, kw = wave & 1;
  int klane = lane >> 3, ulane = lane & 7;
  int k = k0 + kw * 16 + klane * 2;
  int uh = uw * 256;
  const float* ek0p = Ek + ((size_t)b * K_ + k) * NU_;
  const float* ek1p = ek0p + NU_;
  float acc0[8] = {}, acc1[8] = {};
#pragma unroll 2
  for (int j = 0; j < 8; j++) {
    int u = uh + ulane * 4 + 32 * j;
    float4 e0 = *reinterpret_cast<const float4*>(ek0p + u);
    float4 e1 = *reinterpret_cast<const float4*>(ek1p + u);
    float4 v4 = *reinterpret_cast<const float4*>(&sV[u]);
    float e0v[4] = {e0.x, e0.y, e0.z, e0.w};
    float e1v[4] = {e1.x, e1.y, e1.z, e1.w};
    float vv[4] = {v4.x, v4.y, v4.z, v4.w};
#pragma unroll
    for (int qq = 0; qq < 8; qq++) {
      float4 q4 = *reinterpret_cast<const float4*>(&sEq[qq][u]);
      float qv[4] = {q4.x, q4.y, q4.z, q4.w};
#pragma unroll
      for (int i = 0; i < 4; i++) {
        float d0 = fmaf(qv[i], e0v[i], 1.f);
        float d1 = fmaf(qv[i], e1v[i], 1.f);
        acc0[qq] = fmaf(vv[i], __builtin_amdgcn_rcpf(d0), acc0[qq]);
        acc1[qq] = fmaf(vv[i], __builtin_amdgcn_rcpf(d1), acc1[qq]);
      }
    }
  }
  // reduce over the 8 ulane lanes
#pragma unroll
  for (int qq = 0; qq < 8; qq++) {
    acc0[qq] += __shfl_xor(acc0[qq], 1, 64);
    acc0[qq] += __shfl_xor(acc0[qq], 2, 64);
    acc0[qq] += __shfl_xor(acc0[qq], 4, 64);
    acc1[qq] += __shfl_xor(acc1[qq], 1, 64);
    acc1[qq] += __shfl_xor(acc1[qq], 2, 64);
    acc1[qq] += __shfl_xor(acc1[qq], 4, 64);
  }
  if (uw == 1 && ulane == 0) {
#pragma unroll
    for (int qq = 0; qq < 8; qq++) {
      sRed[kw][klane][qq][0] = acc0[qq];
      sRed[kw][klane][qq][1] = acc1[qq];
    }
  }
  __syncthreads();
  if (uw == 0 && ulane == 0) {
#pragma unroll
    for (int qq = 0; qq < 8; qq++) {
      float a0 = acc0[qq] + sRed[kw][klane][qq][0];
      float a1 = acc1[qq] + sRed[kw][klane][qq][1];
      float* sp = S + ((size_t)b * Q_ + q0 + qq) * K_ + k;
      sp[0] = fmaf(-2.f, a0, vtot);
      sp[1] = fmaf(-2.f, a1, vtot);
    }
  }
}

// ---------------------------------------------------------------------------
// Kernel 4: softmax (dt==0) + context with q-register blocking.
// 256 thr: dgroup = t&31 (2 d's), ksplit = t>>5 (8-way k-split).
// ---------------------------------------------------------------------------
__global__ __launch_bounds__(256) void ctx_kernel(
    const float* __restrict__ S, const float* __restrict__ keys,
    float* __restrict__ ctx, float* __restrict__ smx) {
  __shared__ __align__(16) float sS[8][K_];      // 16 KB
  __shared__ __align__(16) float sK[2][64][64];  // 32 KB
  __shared__ float sPart[3][32][16];             // 6 KB
  int b = blockIdx.x >> 3, qt = blockIdx.x & 7, dt = blockIdx.y;
  int q0 = qt * 8, d0 = dt * 64;
  int t = threadIdx.x;
  const float4* ssrc =
      reinterpret_cast<const float4*>(S + ((size_t)b * Q_ + q0) * K_);
#pragma unroll
  for (int i = 0; i < 4; i++)
    reinterpret_cast<float4*>(&sS[0][0])[t + 256 * i] = ssrc[t + 256 * i];
  const float* keysb = keys + (size_t)b * K_ * D_ + d0;
#pragma unroll
  for (int i = t; i < 1024; i += 256) {
    int row = i >> 4, c4 = i & 15;
    reinterpret_cast<float4*>(&sK[0][row][0])[c4] =
        *reinterpret_cast<const float4*>(&keysb[(size_t)row * D_ + c4 * 4]);
  }
  __syncthreads();

  // ---- softmax (32-lane group per q) ----
  {
    int q = t >> 5, lg = t & 31;
    float m = -1e30f;
    for (int kk = lg; kk < K_; kk += 32) m = fmaxf(m, sS[q][kk]);
#pragma unroll
    for (int o = 1; o < 32; o <<= 1) m = fmaxf(m, __shfl_xor(m, o, 64));
    const float L2E = 1.4426950408889634f;
    float sum = 0.f;
    for (int kk = lg; kk < K_; kk += 32)
      sum += __builtin_amdgcn_exp2f((sS[q][kk] - m) * L2E);
#pragma unroll
    for (int o = 1; o < 32; o <<= 1) sum += __shfl_xor(sum, o, 64);
    if (dt == 0) {
      float inv = 1.f / sum;
      float* dst = smx + ((size_t)b * Q_ + q0 + q) * K_;
      for (int kk = lg; kk < K_; kk += 32)
        dst[kk] = __builtin_amdgcn_exp2f((sS[q][kk] - m) * L2E) * inv;
    }
  }

  // ---- context: acc[8q][2d] per thread, 8-way k-split ----
  int dgroup = t & 31, ksplit = t >> 5;
  float acc[8][2] = {};
  int cur = 0;
  for (int kc = 0; kc < K_; kc += 64) {
    if (kc + 64 < K_) {
      const float* kn = keysb + (size_t)(kc + 64) * D_;
      for (int i = t; i < 1024; i += 256) {
        int row = i >> 4, c4 = i & 15;
        reinterpret_cast<float4*>(&sK[cur ^ 1][row][0])[c4] =
            *reinterpret_cast<const float4*>(&kn[(size_t)row * D_ + c4 * 4]);
      }
    }
#pragma unroll
    for (int i = 0; i < 8; i++) {
      int kk = ksplit * 8 + i;
      float2 kv = *reinterpret_cast<const float2*>(&sK[cur][kk][dgroup * 2]);
#pragma unroll
      for (int qq = 0; qq < 8; qq++) {
        float s = sS[qq][kc + kk];
        acc[qq][0] = fmaf(s, kv.x, acc[qq][0]);
        acc[qq][1] = fmaf(s, kv.y, acc[qq][1]);
      }
    }
    __syncthreads();
    cur ^= 1;
  }
  // reduce over ksplit: xor-32 shuffle pairs waves' halves, then LDS
  int wave = t >> 6, lane = t & 63;
#pragma unroll
  for (int qq = 0; qq < 8; qq++) {
    acc[qq][0] += __shfl_xor(acc[qq][0], 32, 64);
    acc[qq][1] += __shfl_xor(acc[qq][1], 32, 64);
  }
  if (wave > 0 && lane < 32) {
#pragma unroll
    for (int qq = 0; qq < 8; qq++) {
      sPart[wave - 1][lane][qq * 2] = acc[qq][0];
      sPart[wave - 1][lane][qq * 2 + 1] = acc[qq][1];
    }
  }
  __syncthreads();
  if (wave == 0 && lane < 32) {
#pragma unroll
    for (int qq = 0; qq < 8; qq++) {
      float c0 = acc[qq][0] + sPart[0][lane][qq * 2] +
                 sPart[1][lane][qq * 2] + sPart[2][lane][qq * 2];
      float c1 = acc[qq][1] + sPart[0][lane][qq * 2 + 1] +
                 sPart[1][lane][qq * 2 + 1] + sPart[2][lane][qq * 2 + 1];
      float2 o2 = {c0, c1};
      *reinterpret_cast<float2*>(
          &ctx[((size_t)b * Q_ + q0 + qq) * D_ + d0 + lane * 2]) = o2;
    }
  }
}

// ---------------------------------------------------------------------------
extern "C" void kernel_launch(void* const* d_in, const int* in_sizes, int n_in,
                              void* d_out, int out_size, void* d_ws,
                              size_t ws_size, hipStream_t stream) {
  const float* query = (const float*)d_in[0];
  const float* keys = (const float*)d_in[1];
  const float* Wq = (const float*)d_in[2];
  const float* Wk = (const float*)d_in[3];
  const float* la = (const float*)d_in[4];
  const float* nscalar = (const float*)d_in[5];
  const float* nbias = (const float*)d_in[6];

  float* out = (float*)d_out;
  float* ctx = out;
  float* smx = out + (size_t)B_ * Q_ * D_;

  float* ws = (float*)d_ws;
  float* v = ws + WS_V;
  float* Eq = ws + WS_EQ;
  float* Ek = ws + WS_EK;
  float* S = ws + WS_S;

  if (ws_size >= (size_t)WS_BYTES_MFMA) {
    _Float16* Ah = (_Float16*)(ws + WS_FLOATS);
    _Float16* Wkh = Ah + AH_ELEMS;
    _Float16* Wqh = Wkh + WH_ELEMS;
    convert_kernel<<<CONV_BLOCKS + 1, 256, 0, stream>>>(
        query, keys, Wq, Wk, la, nscalar, Ah, Wkh, Wqh, v);
    mfma_proj_kernel<<<dim3(72, 8), 256, 0, stream>>>(Ah, Wkh, Wqh, nbias, Ek,
                                                      Eq);
  } else {
    compute_v_kernel<<<1, 512, 0, stream>>>(la, nscalar, v);
    proj_gemm_kernel<<<dim3(72, 8), 256, 0, stream>>>(query, keys, Wq, Wk,
                                                      nbias, Eq, Ek);
  }
  scores_kernel<<<dim3(64, 16), 256, 0, stream>>>(Eq, Ek, v, S);
  ctx_kernel<<<dim3(64, 8), 256, 0, stream>>>(S, keys, ctx, smx);
}